// Round 4
// baseline (28.080 us; speedup 1.0000x reference)
//
#include <hip/hip_runtime.h>

// Sparsemax over last axis. B=8, N=4096, D=512, fp32 in/out.
// One 64-lane wave handles TWO rows (interleaved) to double ILP inside the
// latency-critical Michelot iteration. 8 values/lane/row in registers.
// tau0 = rowmax - 1 (valid: max weight <= 1). Counts via ballot+popcount.
// Non-temporal loads/stores (native clang vector type, not HIP_vector_type).

constexpr int D   = 512;
constexpr int NW  = 64;
constexpr int VPT = D / NW;    // 8 values per lane per row

typedef float f32x4 __attribute__((ext_vector_type(4)));

__global__ __launch_bounds__(256)
void sparsemax_kernel(const float* __restrict__ in, float* __restrict__ out,
                      int nrows) {
    const int lane = threadIdx.x & (NW - 1);
    const int wave = threadIdx.x >> 6;
    const int rowA = (blockIdx.x * 4 + wave) * 2;   // 8 rows per block
    const int rowB = rowA + 1;
    if (rowA >= nrows) return;

    const f32x4* rpA = reinterpret_cast<const f32x4*>(in + (size_t)rowA * D);
    const f32x4* rpB = reinterpret_cast<const f32x4*>(in + (size_t)rowB * D);

    const f32x4 a0 = __builtin_nontemporal_load(rpA + lane);
    const f32x4 a1 = __builtin_nontemporal_load(rpA + NW + lane);
    const f32x4 b0 = __builtin_nontemporal_load(rpB + lane);
    const f32x4 b1 = __builtin_nontemporal_load(rpB + NW + lane);

    float va[VPT] = {a0.x, a0.y, a0.z, a0.w, a1.x, a1.y, a1.z, a1.w};
    float vb[VPT] = {b0.x, b0.y, b0.z, b0.w, b1.x, b1.y, b1.z, b1.w};

    // ---- wave max, both rows interleaved ----
    float ma = va[0], mb = vb[0];
#pragma unroll
    for (int i = 1; i < VPT; ++i) { ma = fmaxf(ma, va[i]); mb = fmaxf(mb, vb[i]); }
#pragma unroll
    for (int off = 32; off; off >>= 1) {
        ma = fmaxf(ma, __shfl_xor(ma, off, NW));
        mb = fmaxf(mb, __shfl_xor(mb, off, NW));
    }

    // ---- Michelot fixed-point from tau0 = max - 1, two chains interleaved ----
    float tauA = ma - 1.0f, tauB = mb - 1.0f;
    int   prevA = 1 << 30,  prevB = 1 << 30;
    bool  doneA = false,    doneB = false;
    for (int it = 0; it < D; ++it) {
        float psA = 0.f, psB = 0.f;
        int   pcA = 0,   pcB = 0;
#pragma unroll
        for (int i = 0; i < VPT; ++i) {
            const bool gA = va[i] > tauA;
            const bool gB = vb[i] > tauB;
            psA += gA ? va[i] : 0.0f;
            psB += gB ? vb[i] : 0.0f;
            pcA += (int)__popcll(__ballot(gA));
            pcB += (int)__popcll(__ballot(gB));
        }
#pragma unroll
        for (int off = 32; off; off >>= 1) {
            psA += __shfl_xor(psA, off, NW);
            psB += __shfl_xor(psB, off, NW);
        }
        if (!doneA) tauA = (psA - 1.0f) / (float)pcA;
        if (!doneB) tauB = (psB - 1.0f) / (float)pcB;
        doneA = doneA || (pcA >= prevA);
        doneB = doneB || (pcB >= prevB);
        if (doneA && doneB) break;
        prevA = pcA; prevB = pcB;
    }

    // ---- output: relu(z - tau), non-temporal float4 stores ----
    f32x4* opA = reinterpret_cast<f32x4*>(out + (size_t)rowA * D);
    f32x4* opB = reinterpret_cast<f32x4*>(out + (size_t)rowB * D);
    f32x4 oa0, oa1, ob0, ob1;
    oa0.x = fmaxf(va[0] - tauA, 0.0f);  oa0.y = fmaxf(va[1] - tauA, 0.0f);
    oa0.z = fmaxf(va[2] - tauA, 0.0f);  oa0.w = fmaxf(va[3] - tauA, 0.0f);
    oa1.x = fmaxf(va[4] - tauA, 0.0f);  oa1.y = fmaxf(va[5] - tauA, 0.0f);
    oa1.z = fmaxf(va[6] - tauA, 0.0f);  oa1.w = fmaxf(va[7] - tauA, 0.0f);
    ob0.x = fmaxf(vb[0] - tauB, 0.0f);  ob0.y = fmaxf(vb[1] - tauB, 0.0f);
    ob0.z = fmaxf(vb[2] - tauB, 0.0f);  ob0.w = fmaxf(vb[3] - tauB, 0.0f);
    ob1.x = fmaxf(vb[4] - tauB, 0.0f);  ob1.y = fmaxf(vb[5] - tauB, 0.0f);
    ob1.z = fmaxf(vb[6] - tauB, 0.0f);  ob1.w = fmaxf(vb[7] - tauB, 0.0f);
    __builtin_nontemporal_store(oa0, opA + lane);
    __builtin_nontemporal_store(oa1, opA + NW + lane);
    __builtin_nontemporal_store(ob0, opB + lane);
    __builtin_nontemporal_store(ob1, opB + NW + lane);
}

extern "C" void kernel_launch(void* const* d_in, const int* in_sizes, int n_in,
                              void* d_out, int out_size, void* d_ws, size_t ws_size,
                              hipStream_t stream) {
    const float* in  = (const float*)d_in[0];   // inputs [B,N,D]; mask unused
    float*       out = (float*)d_out;
    const int nrows = out_size / D;             // 32768

    const int rows_per_block = 8;               // 4 waves x 2 rows
    const int grid = (nrows + rows_per_block - 1) / rows_per_block;
    sparsemax_kernel<<<grid, 256, 0, stream>>>(in, out, nrows);
}

// Round 5
// 25.744 us; speedup vs baseline: 1.0907x; 1.0907x over previous
//
#include <hip/hip_runtime.h>

// Sparsemax over last axis. B=8, N=4096, D=512, fp32 in/out.
// One 64-lane wave per row, 8 values/lane. Each wave processes 4 rows
// SEQUENTIALLY with next-row loads prefetched before the current row's
// Michelot loop (hides HBM latency under the ~1300cy serial compute chain).
// tau0 = rowmax - 1 (valid lower bound: max weight <= 1). Counts via
// ballot+popcount (scalar pipe). tau update uses v_rcp_f32 (1 ulp; fine
// for 2e-2 threshold). Stores are non-temporal (write-once stream);
// loads stay cached (L3 serves ~half the fetches per R1/R2 counters).

constexpr int D   = 512;
constexpr int NW  = 64;
constexpr int VPT = D / NW;    // 8 values per lane
constexpr int RPW = 4;         // rows per wave, sequential

typedef float f32x4 __attribute__((ext_vector_type(4)));

__global__ __launch_bounds__(256)
void sparsemax_kernel(const float* __restrict__ in, float* __restrict__ out,
                      int nrows) {
    const int lane = threadIdx.x & (NW - 1);
    const int wave = threadIdx.x >> 6;
    const int row0 = (blockIdx.x * 4 + wave) * RPW;
    if (row0 >= nrows) return;

    const f32x4* ip = reinterpret_cast<const f32x4*>(in)  + (size_t)row0 * (D / 4);
    f32x4*       op = reinterpret_cast<f32x4*>(out)       + (size_t)row0 * (D / 4);

    // current row's data
    f32x4 c0 = ip[lane];
    f32x4 c1 = ip[NW + lane];

#pragma unroll
    for (int r = 0; r < RPW; ++r) {
        // ---- prefetch next row before compute ----
        f32x4 n0 = c0, n1 = c1;
        if (r + 1 < RPW) {
            const f32x4* np = ip + (size_t)(r + 1) * (D / 4);
            n0 = np[lane];
            n1 = np[NW + lane];
        }

        float v[VPT] = {c0.x, c0.y, c0.z, c0.w, c1.x, c1.y, c1.z, c1.w};

        // ---- wave max ----
        float m = v[0];
#pragma unroll
        for (int i = 1; i < VPT; ++i) m = fmaxf(m, v[i]);
#pragma unroll
        for (int off = 32; off; off >>= 1) m = fmaxf(m, __shfl_xor(m, off, NW));

        // ---- Michelot fixed-point from tau0 = max - 1 ----
        float tau  = m - 1.0f;
        int   prev = 1 << 30;
        for (int it = 0; it < D; ++it) {
            float ps = 0.f;
            int   pc = 0;
#pragma unroll
            for (int i = 0; i < VPT; ++i) {
                const bool g = v[i] > tau;
                ps += g ? v[i] : 0.0f;
                pc += (int)__popcll(__ballot(g));   // vcc reuse -> s_bcnt1_b64
            }
#pragma unroll
            for (int off = 32; off; off >>= 1) ps += __shfl_xor(ps, off, NW);
            tau = (ps - 1.0f) * __builtin_amdgcn_rcpf((float)pc);  // pc >= 1
            if (pc >= prev) break;                  // support stopped shrinking
            prev = pc;
        }

        // ---- output: relu(z - tau), non-temporal float4 stores ----
        f32x4 o0, o1;
        o0.x = fmaxf(v[0] - tau, 0.0f);  o0.y = fmaxf(v[1] - tau, 0.0f);
        o0.z = fmaxf(v[2] - tau, 0.0f);  o0.w = fmaxf(v[3] - tau, 0.0f);
        o1.x = fmaxf(v[4] - tau, 0.0f);  o1.y = fmaxf(v[5] - tau, 0.0f);
        o1.z = fmaxf(v[6] - tau, 0.0f);  o1.w = fmaxf(v[7] - tau, 0.0f);
        f32x4* opr = op + (size_t)r * (D / 4);
        __builtin_nontemporal_store(o0, opr + lane);
        __builtin_nontemporal_store(o1, opr + NW + lane);

        c0 = n0; c1 = n1;
    }
}

extern "C" void kernel_launch(void* const* d_in, const int* in_sizes, int n_in,
                              void* d_out, int out_size, void* d_ws, size_t ws_size,
                              hipStream_t stream) {
    const float* in  = (const float*)d_in[0];   // inputs [B,N,D]; mask unused
    float*       out = (float*)d_out;
    const int nrows = out_size / D;             // 32768

    const int rows_per_block = 4 * RPW;         // 4 waves x 4 sequential rows
    const int grid = (nrows + rows_per_block - 1) / rows_per_block;  // 2048
    sparsemax_kernel<<<grid, 256, 0, stream>>>(in, out, nrows);
}

// Round 6
// 22.632 us; speedup vs baseline: 1.2407x; 1.1375x over previous
//
#include <hip/hip_runtime.h>

// Sparsemax over last axis. B=8, N=4096, D=512, fp32 in/out.
// R2 structure (best so far): one 64-lane wave per row, 8 vals/lane,
// 32768 independent waves for max TLP.
// Changes vs R2:
//  - butterfly reductions use DPP for xor1/2/4/8 (VALU pipe, low latency)
//    and __shfl_xor only for the 16/32 cross-row steps;
//  - tau update uses v_rcp_f32 (1 ulp; threshold is 2e-2);
//  - non-temporal stores (write-once stream; keep input L3-resident).
// tau0 = rowmax - 1 (valid: tau* >= max-1 since max weight <= 1), so the
// initial support is the ~dozen elements above max-1, and Michelot
// converges in ~3-4 iterations.

constexpr int D   = 512;
constexpr int NW  = 64;
constexpr int VPT = D / NW;    // 8 values per lane

typedef float f32x4 __attribute__((ext_vector_type(4)));

// DPP ctrl values: quad_perm(1,0,3,2)=0xB1 (xor1), quad_perm(2,3,0,1)=0x4E
// (xor2), row_half_mirror=0x141 (pairs 4-groups within 8), row_mirror=0x140
// (pairs 8-groups within 16). Valid butterfly steps because values are
// uniform within 2^(k-1) groups after step k-1.
template <int CTRL>
__device__ __forceinline__ float dpp_mov_f32(float x) {
    return __builtin_bit_cast(float,
        __builtin_amdgcn_update_dpp(0, __builtin_bit_cast(int, x),
                                    CTRL, 0xF, 0xF, true));
}

__device__ __forceinline__ float wave_sum(float x) {
    x += dpp_mov_f32<0xB1>(x);
    x += dpp_mov_f32<0x4E>(x);
    x += dpp_mov_f32<0x141>(x);
    x += dpp_mov_f32<0x140>(x);
    x += __shfl_xor(x, 16, NW);
    x += __shfl_xor(x, 32, NW);
    return x;
}

__device__ __forceinline__ float wave_max(float x) {
    x = fmaxf(x, dpp_mov_f32<0xB1>(x));
    x = fmaxf(x, dpp_mov_f32<0x4E>(x));
    x = fmaxf(x, dpp_mov_f32<0x141>(x));
    x = fmaxf(x, dpp_mov_f32<0x140>(x));
    x = fmaxf(x, __shfl_xor(x, 16, NW));
    x = fmaxf(x, __shfl_xor(x, 32, NW));
    return x;
}

__global__ __launch_bounds__(256)
void sparsemax_kernel(const float* __restrict__ in, float* __restrict__ out,
                      int nrows) {
    const int lane = threadIdx.x & (NW - 1);
    const int wave = threadIdx.x >> 6;
    const int row  = blockIdx.x * 4 + wave;
    if (row >= nrows) return;

    const f32x4* rp = reinterpret_cast<const f32x4*>(in + (size_t)row * D);
    f32x4*       op = reinterpret_cast<f32x4*>(out + (size_t)row * D);

    const f32x4 a = rp[lane];
    const f32x4 b = rp[NW + lane];
    float v[VPT] = {a.x, a.y, a.z, a.w, b.x, b.y, b.z, b.w};

    // ---- wave max ----
    float m = v[0];
#pragma unroll
    for (int i = 1; i < VPT; ++i) m = fmaxf(m, v[i]);
    m = wave_max(m);

    // ---- Michelot fixed-point from tau0 = max - 1 ----
    float tau  = m - 1.0f;
    int   prev = 1 << 30;
    for (int it = 0; it < D; ++it) {
        float ps = 0.f;
        int   pc = 0;
#pragma unroll
        for (int i = 0; i < VPT; ++i) {
            const bool g = v[i] > tau;
            ps += g ? v[i] : 0.0f;
            pc += (int)__popcll(__ballot(g));   // reuses the v_cmp; s_bcnt1_b64
        }
        ps = wave_sum(ps);
        tau = (ps - 1.0f) * __builtin_amdgcn_rcpf((float)pc);  // pc >= 1
        if (pc >= prev) break;                  // support stopped shrinking
        prev = pc;
    }

    // ---- output: relu(z - tau), non-temporal float4 stores ----
    f32x4 o0, o1;
    o0.x = fmaxf(v[0] - tau, 0.0f);  o0.y = fmaxf(v[1] - tau, 0.0f);
    o0.z = fmaxf(v[2] - tau, 0.0f);  o0.w = fmaxf(v[3] - tau, 0.0f);
    o1.x = fmaxf(v[4] - tau, 0.0f);  o1.y = fmaxf(v[5] - tau, 0.0f);
    o1.z = fmaxf(v[6] - tau, 0.0f);  o1.w = fmaxf(v[7] - tau, 0.0f);
    __builtin_nontemporal_store(o0, op + lane);
    __builtin_nontemporal_store(o1, op + NW + lane);
}

extern "C" void kernel_launch(void* const* d_in, const int* in_sizes, int n_in,
                              void* d_out, int out_size, void* d_ws, size_t ws_size,
                              hipStream_t stream) {
    const float* in  = (const float*)d_in[0];   // inputs [B,N,D]; mask unused
    float*       out = (float*)d_out;
    const int nrows = out_size / D;             // 32768

    const int grid = (nrows + 3) / 4;           // 4 waves/block, 1 row/wave
    sparsemax_kernel<<<grid, 256, 0, stream>>>(in, out, nrows);
}